// Round 11
// baseline (217.322 us; speedup 1.0000x reference)
//
#include <hip/hip_runtime.h>
#include <hip/hip_bf16.h>

#define D 128
#define NCLS 10

typedef short bf16x8 __attribute__((ext_vector_type(8)));
typedef float f32x4 __attribute__((ext_vector_type(4)));

typedef __attribute__((address_space(1))) const unsigned int gas_u32;
typedef __attribute__((address_space(3))) unsigned int las_u32;
static __device__ __forceinline__ void gload16(const ushort* g, ushort* l){
  __builtin_amdgcn_global_load_lds((gas_u32*)g, (las_u32*)l, 16, 0, 0);
}

static __device__ __forceinline__ float relu(float x){ return fmaxf(x, 0.0f); }
static __device__ __forceinline__ float bf_lo(unsigned v){ return __uint_as_float(v << 16); }
static __device__ __forceinline__ float bf_hi(unsigned v){ return __uint_as_float(v & 0xffff0000u); }
static __device__ __forceinline__ ushort bf16u(float f){
  __hip_bfloat16 h = __float2bfloat16(f);
  return *reinterpret_cast<ushort*>(&h);
}
static __device__ __forceinline__ unsigned relu_bf2(unsigned v){
  if (v & 0x00008000u) v &= 0xFFFF0000u;
  if (v & 0x80000000u) v &= 0x0000FFFFu;
  return v;
}

// fused: zero counts+cursor (nz ints) || transpose+convert W1,W2 -> bf16 W^T
__global__ __launch_bounds__(256) void k_init(int* __restrict__ counts2, int nz,
                                              const float* __restrict__ W1,
                                              const float* __restrict__ W2,
                                              ushort* __restrict__ Wt1,
                                              ushort* __restrict__ Wt2){
  const int nzb = (nz + 255) >> 8;
  const int b = blockIdx.x;
  if (b < nzb){
    int i = b*256 + threadIdx.x;
    if (i < nz) counts2[i] = 0;
  } else {
    int i = (b - nzb)*256 + threadIdx.x;   // [0, 32768)
    int sel = i >> 14;
    int rem = i & 16383;
    int k = rem >> 7, n = rem & 127;
    const float* Ws = sel ? W2 : W1;
    ushort* Wd = sel ? Wt2 : Wt1;
    Wd[n*128 + k] = bf16u(Ws[rem]);
  }
}

// histogram, 2 edges/thread via int2
__global__ __launch_bounds__(256) void k_hist(const int* __restrict__ dst,
                                              int* __restrict__ counts, int E){
  int i = blockIdx.x*256 + threadIdx.x;
  int e0 = 2*i;
  if (e0 + 1 < E){
    int2 d = ((const int2*)dst)[i];
    atomicAdd(counts + d.x, 1);
    atomicAdd(counts + d.y, 1);
  } else if (e0 < E){
    atomicAdd(counts + dst[e0], 1);
  }
}

// per-block scan: rowPtr2[i] = {block-local beg, block-local end}; bsum; dinv
__global__ __launch_bounds__(256) void k_scan1(const int* __restrict__ counts,
                                               int2* __restrict__ rowPtr2,
                                               int* __restrict__ bsum,
                                               float* __restrict__ dinv, int n){
  const int i = blockIdx.x*256 + threadIdx.x;
  const int lane = threadIdx.x & 63;
  const int wid  = threadIdx.x >> 6;
  int v = (i < n) ? counts[i] : 0;
  if (i < n) dinv[i] = rsqrtf((float)(v + 1));   // +1 self-loop
  int s = v;
  #pragma unroll
  for (int off = 1; off < 64; off <<= 1){
    int u = __shfl_up(s, off, 64);
    if (lane >= off) s += u;
  }
  __shared__ int ws[4];
  if (lane == 63) ws[wid] = s;
  __syncthreads();
  int add = 0;
  if (wid >= 1) add += ws[0];
  if (wid >= 2) add += ws[1];
  if (wid >= 3) add += ws[2];
  int incl = s + add;
  if (i < n) rowPtr2[i] = make_int2(incl - v, incl);
  if (threadIdx.x == 255) bsum[blockIdx.x] = incl;
}

// single block: exclusive scan of bsum[0..nb), nb <= 256
__global__ __launch_bounds__(256) void k_scan2(int* __restrict__ bsum, int nb){
  const int t = threadIdx.x;
  const int lane = t & 63;
  const int wid  = t >> 6;
  int v = (t < nb) ? bsum[t] : 0;
  int s = v;
  #pragma unroll
  for (int off = 1; off < 64; off <<= 1){
    int u = __shfl_up(s, off, 64);
    if (lane >= off) s += u;
  }
  __shared__ int ws[4];
  if (lane == 63) ws[wid] = s;
  __syncthreads();
  int add = 0;
  if (wid >= 1) add += ws[0];
  if (wid >= 2) add += ws[1];
  if (wid >= 3) add += ws[2];
  int incl = s + add;
  if (t < nb) bsum[t] = incl - v;     // exclusive block offset
}

// scatter edge -> CSR slot (bsum added inline); store {src, dinv[src]}
__global__ __launch_bounds__(256) void k_scatter(const int* __restrict__ src,
                                                 const int* __restrict__ dst,
                                                 const int2* __restrict__ rowPtr2,
                                                 const int* __restrict__ bsum,
                                                 const float* __restrict__ dinv,
                                                 int* __restrict__ cursor,
                                                 int2* __restrict__ edat, int E){
  int i = blockIdx.x*256 + threadIdx.x;
  if (i >= E) return;
  int d = dst[i];
  int s = src[i];
  int pos = rowPtr2[d].x + bsum[d >> 8] + atomicAdd(cursor + d, 1);
  edat[pos] = make_int2(s, __float_as_int(dinv[s]));
}

// C(bf16)[M,128] = maybe_relu(A) @ W, via MFMA 16x16x32 bf16 (R7-proven).
template<bool BF16IN, bool RELU>
__global__ __launch_bounds__(256) void k_gemm_mfma(const void* __restrict__ Av,
                                                   const ushort* __restrict__ Wt,
                                                   __hip_bfloat16* __restrict__ C,
                                                   int M){
  __shared__ ushort sA[64*136];
  __shared__ ushort sW[128*136];
  const int tid = threadIdx.x;
  const int row0 = blockIdx.x * 64;
  const int rowsHere = (M - row0 >= 64) ? 64 : (M - row0);

  {
    const uint4* Wt4 = (const uint4*)Wt;
    for (int i = tid; i < 2048; i += 256){
      int r = i >> 4, c = i & 15;
      uint4 v = Wt4[i];
      *((uint4*)(sW + r*136 + c*8)) = v;
    }
  }
  if (BF16IN){
    const uint4* A4 = (const uint4*)((const ushort*)Av + (size_t)row0 * D);
    for (int i = tid; i < 64*16; i += 256){
      int r = i >> 4, c = i & 15;
      uint4 v = make_uint4(0,0,0,0);
      if (r < rowsHere) v = A4[i];
      if (RELU){ v.x = relu_bf2(v.x); v.y = relu_bf2(v.y);
                 v.z = relu_bf2(v.z); v.w = relu_bf2(v.w); }
      *((uint4*)(sA + r*136 + c*8)) = v;
    }
  } else {
    const float4* A4 = (const float4*)Av + (size_t)row0 * 32;
    for (int i = tid; i < 64*32; i += 256){
      int r = i >> 5, c = i & 31;
      float4 v = make_float4(0.f,0.f,0.f,0.f);
      if (r < rowsHere) v = A4[i];
      if (RELU){ v.x=relu(v.x); v.y=relu(v.y); v.z=relu(v.z); v.w=relu(v.w); }
      ushort4 p;
      p.x = bf16u(v.x); p.y = bf16u(v.y); p.z = bf16u(v.z); p.w = bf16u(v.w);
      *((ushort4*)(sA + r*136 + c*4)) = p;
    }
  }
  __syncthreads();

  const int wid  = tid >> 6;
  const int lane = tid & 63;
  const int fr = lane & 15;
  const int fq = lane >> 4;
  const ushort* aBase = sA + (wid*16 + fr)*136 + fq*8;
  const ushort* wBase = sW + fr*136 + fq*8;

  f32x4 acc0 = {0.f,0.f,0.f,0.f}, acc1 = acc0, acc2 = acc0, acc3 = acc0;
  f32x4 acc4 = acc0, acc5 = acc0, acc6 = acc0, acc7 = acc0;
  #pragma unroll
  for (int ks = 0; ks < 4; ++ks){
    bf16x8 a = *(const bf16x8*)(aBase + ks*32);
    bf16x8 b;
    b = *(const bf16x8*)(wBase + 0*16*136 + ks*32);
    acc0 = __builtin_amdgcn_mfma_f32_16x16x32_bf16(a, b, acc0, 0, 0, 0);
    b = *(const bf16x8*)(wBase + 1*16*136 + ks*32);
    acc1 = __builtin_amdgcn_mfma_f32_16x16x32_bf16(a, b, acc1, 0, 0, 0);
    b = *(const bf16x8*)(wBase + 2*16*136 + ks*32);
    acc2 = __builtin_amdgcn_mfma_f32_16x16x32_bf16(a, b, acc2, 0, 0, 0);
    b = *(const bf16x8*)(wBase + 3*16*136 + ks*32);
    acc3 = __builtin_amdgcn_mfma_f32_16x16x32_bf16(a, b, acc3, 0, 0, 0);
    b = *(const bf16x8*)(wBase + 4*16*136 + ks*32);
    acc4 = __builtin_amdgcn_mfma_f32_16x16x32_bf16(a, b, acc4, 0, 0, 0);
    b = *(const bf16x8*)(wBase + 5*16*136 + ks*32);
    acc5 = __builtin_amdgcn_mfma_f32_16x16x32_bf16(a, b, acc5, 0, 0, 0);
    b = *(const bf16x8*)(wBase + 6*16*136 + ks*32);
    acc6 = __builtin_amdgcn_mfma_f32_16x16x32_bf16(a, b, acc6, 0, 0, 0);
    b = *(const bf16x8*)(wBase + 7*16*136 + ks*32);
    acc7 = __builtin_amdgcn_mfma_f32_16x16x32_bf16(a, b, acc7, 0, 0, 0);
  }

  const int rbase = row0 + wid*16 + fq*4;
  #pragma unroll
  for (int r = 0; r < 4; ++r){
    int row = rbase + r;
    if (row < M){
      __hip_bfloat16* crow = C + (size_t)row*D + fr;
      crow[0*16]  = __float2bfloat16(acc0[r]);
      crow[1*16]  = __float2bfloat16(acc1[r]);
      crow[2*16]  = __float2bfloat16(acc2[r]);
      crow[3*16]  = __float2bfloat16(acc3[r]);
      crow[4*16]  = __float2bfloat16(acc4[r]);
      crow[5*16]  = __float2bfloat16(acc5[r]);
      crow[6*16]  = __float2bfloat16(acc6[r]);
      crow[7*16]  = __float2bfloat16(acc7[r]);
    }
  }
}

// Staged gather core: per 32-edge chunk, 8 independent global_load_lds
// (fire-and-forget, zero VGPR), vmcnt(0), then LDS consume with each lane
// owning 2 features (no per-edge shfl, no reduction tail). Tail edges are
// padded with norm=0 against clamped (finite) staged rows.
// After the macro: accx/accy hold f32 sums for feats {2*lane, 2*lane+1}.
#define AGG_CORE_STAGED                                                        \
  const int wv   = threadIdx.x >> 6;                                           \
  const int grp  = lane >> 4;                                                  \
  const int q    = lane & 15;                                                  \
  ushort* rowsW = sRows + wv*(32*128);                                         \
  float*  normW = sNorm + wv*32;                                               \
  float dn = dinv[node];                                                       \
  float accx = 0.f, accy = 0.f;                                                \
  int2 be = rowPtr2[node];                                                     \
  int bs = bsum[node >> 8];                                                    \
  int beg = be.x + bs, end = be.y + bs;                                        \
  for (int j = beg; j < end; j += 32){                                         \
    int rem = end - j;                                                         \
    int cnt = (rem < 32) ? rem : 32;                                           \
    int2 ed = make_int2(0, 0);                                                 \
    float nf = 0.f;                                                            \
    if (lane < cnt){                                                           \
      ed = edat[j + lane];                                                     \
      nf = __uint_as_float((unsigned)ed.y) * dn;                               \
    }                                                                          \
    if (lane < 32) normW[lane] = nf;                                           \
    _Pragma("unroll")                                                          \
    for (int i = 0; i < 8; ++i){                                               \
      int e = i*4 + grp;                                                       \
      e = (e < cnt) ? e : (cnt - 1);                                           \
      int sb = __shfl(ed.x, e, 64);                                            \
      gload16(h + ((size_t)sb << 7) + q*8, rowsW + i*512);                     \
    }                                                                          \
    asm volatile("s_waitcnt vmcnt(0)" ::: "memory");                           \
    int T = (cnt + 3) >> 2;                                                    \
    for (int t = 0; t < T; ++t){                                               \
      _Pragma("unroll")                                                        \
      for (int u = 0; u < 4; ++u){                                             \
        int k = t*4 + u;                                                       \
        float nb = normW[k];                                                   \
        unsigned hv = *(const unsigned*)(rowsW + k*128 + lane*2);              \
        accx += bf_lo(hv)*nb;                                                  \
        accy += bf_hi(hv)*nb;                                                  \
      }                                                                        \
    }                                                                          \
  }

// layer-1 agg: out(bf16)[node] = h*dinv^2 + b + gathered
__global__ __launch_bounds__(256) void k_agg_csr(const ushort* __restrict__ h,
                                                 const int2* __restrict__ rowPtr2,
                                                 const int* __restrict__ bsum,
                                                 const int2* __restrict__ edat,
                                                 const float* __restrict__ dinv,
                                                 const float* __restrict__ b,
                                                 ushort* __restrict__ out, int n){
  __shared__ ushort sRows[4*32*128];   // 32KB: 4 waves x 32 rows x 256B
  __shared__ float  sNorm[4*32];
  int node = blockIdx.x*4 + (threadIdx.x >> 6);
  int lane = threadIdx.x & 63;
  if (node >= n) return;
  AGG_CORE_STAGED
  unsigned hs = *(const unsigned*)(h + ((size_t)node << 7) + lane*2);
  float2 bv = ((const float2*)b)[lane];
  float sl = dn * dn;
  float r0 = accx + bf_lo(hs)*sl + bv.x;
  float r1 = accy + bf_hi(hs)*sl + bv.y;
  unsigned po = ((unsigned)bf16u(r1) << 16) | (unsigned)bf16u(r0);
  *(unsigned*)(out + ((size_t)node << 7) + lane*2) = po;
}

// layer-2 agg fused with head: relu(agg) @ Wl + bl -> log_softmax
__global__ __launch_bounds__(256) void k_agg_head(const ushort* __restrict__ h,
                                                  const int2* __restrict__ rowPtr2,
                                                  const int* __restrict__ bsum,
                                                  const int2* __restrict__ edat,
                                                  const float* __restrict__ dinv,
                                                  const float* __restrict__ b,
                                                  const float* __restrict__ Wl,
                                                  const float* __restrict__ bl,
                                                  float* __restrict__ out, int n){
  __shared__ ushort sRows[4*32*128];
  __shared__ float  sNorm[4*32];
  int node = blockIdx.x*4 + (threadIdx.x >> 6);
  int lane = threadIdx.x & 63;
  if (node >= n) return;
  AGG_CORE_STAGED
  unsigned hs = *(const unsigned*)(h + ((size_t)node << 7) + lane*2);
  float2 bv = ((const float2*)b)[lane];
  float sl = dn * dn;
  float r0 = relu(accx + bf_lo(hs)*sl + bv.x);
  float r1 = relu(accy + bf_hi(hs)*sl + bv.y);
  const float* wl0 = Wl + (2*lane)*NCLS;
  float lacc[NCLS];
  #pragma unroll
  for (int c = 0; c < NCLS; ++c)
    lacc[c] = r0 * wl0[c] + r1 * wl0[NCLS + c];
  #pragma unroll
  for (int c = 0; c < NCLS; ++c){
    #pragma unroll
    for (int off = 32; off >= 1; off >>= 1)
      lacc[c] += __shfl_xor(lacc[c], off, 64);
    lacc[c] += bl[c];
  }
  float m = lacc[0];
  #pragma unroll
  for (int c = 1; c < NCLS; ++c) m = fmaxf(m, lacc[c]);
  float se = 0.f;
  #pragma unroll
  for (int c = 0; c < NCLS; ++c) se += expf(lacc[c] - m);
  float lse = m + logf(se);
  if (lane < NCLS){
    float v = lacc[0];
    #pragma unroll
    for (int c = 1; c < NCLS; ++c) if (lane == c) v = lacc[c];
    out[(size_t)node*NCLS + lane] = v - lse;
  }
}

extern "C" void kernel_launch(void* const* d_in, const int* in_sizes, int n_in,
                              void* d_out, int out_size, void* d_ws, size_t ws_size,
                              hipStream_t stream){
  const float* x  = (const float*)d_in[0];
  const int*   ei = (const int*)d_in[1];
  const float* W1 = (const float*)d_in[2];
  const float* b1 = (const float*)d_in[3];
  const float* W2 = (const float*)d_in[4];
  const float* b2 = (const float*)d_in[5];
  const float* Wl = (const float*)d_in[6];
  const float* bl = (const float*)d_in[7];
  float* out = (float*)d_out;

  const int N = in_sizes[0] / D;     // 50000
  const int E = in_sizes[1] / 2;     // 800000
  const int* src = ei;
  const int* dst = ei + E;

  char* ws = (char*)d_ws;
  size_t off = 0;
  ushort* h1    = (ushort*)(ws + off); off += (size_t)N*D*2;
  ushort* g1    = (ushort*)(ws + off); off += (size_t)N*D*2;
  ushort* h2    = (ushort*)(ws + off); off += (size_t)N*D*2;
  ushort* Wt1   = (ushort*)(ws + off); off += (size_t)128*128*2;
  ushort* Wt2   = (ushort*)(ws + off); off += (size_t)128*128*2;
  int*   counts = (int*)(ws + off);    off += (size_t)N*4;
  int*   cursor = (int*)(ws + off);    off += (size_t)N*4;    // adjacent to counts
  int2*  rowPtr2= (int2*)(ws + off);   off += (size_t)N*8;
  float* dinv   = (float*)(ws + off);  off += (size_t)N*4;
  int*   bsum   = (int*)(ws + off);    off += (size_t)256*4;
  int2*  edat   = (int2*)(ws + off);   off += (size_t)E*8;

  const int nbN   = (N + 255)/256;     // 196 (<=256 for scan2)
  const int nb2N  = (2*N + 255)/256;   // 391
  const int nbE   = (E + 255)/256;
  const int nbE2  = (E/2 + 255)/256;
  const int initB = nb2N + 128;        // zero || cvtW
  const int gemmB = (N + 63)/64;
  const int aggB  = (N + 3)/4;         // 1 wave per node

  // CSR build + weight transpose
  k_init<<<initB, 256, 0, stream>>>(counts, 2*N, W1, W2, Wt1, Wt2);
  k_hist<<<nbE2, 256, 0, stream>>>(dst, counts, E);
  k_scan1<<<nbN, 256, 0, stream>>>(counts, rowPtr2, bsum, dinv, N);
  k_scan2<<<1, 256, 0, stream>>>(bsum, nbN);
  k_scatter<<<nbE, 256, 0, stream>>>(src, dst, rowPtr2, bsum, dinv, cursor, edat, E);

  // layer 1
  k_gemm_mfma<false,false><<<gemmB, 256, 0, stream>>>(x, Wt1, (__hip_bfloat16*)h1, N);
  k_agg_csr<<<aggB, 256, 0, stream>>>(h1, rowPtr2, bsum, edat, dinv, b1, g1, N);

  // layer 2 (relu fused into GEMM staging; head fused into aggregation)
  k_gemm_mfma<true,true><<<gemmB, 256, 0, stream>>>(g1, Wt2, (__hip_bfloat16*)h2, N);
  k_agg_head<<<aggB, 256, 0, stream>>>(h2, rowPtr2, bsum, edat, dinv, b2, Wl, bl, out, N);
}

// Round 12
// 207.424 us; speedup vs baseline: 1.0477x; 1.0477x over previous
//
#include <hip/hip_runtime.h>
#include <hip/hip_bf16.h>

#define D 128
#define NCLS 10

typedef short bf16x8 __attribute__((ext_vector_type(8)));
typedef float f32x4 __attribute__((ext_vector_type(4)));

static __device__ __forceinline__ float relu(float x){ return fmaxf(x, 0.0f); }
static __device__ __forceinline__ float bf_lo(unsigned v){ return __uint_as_float(v << 16); }
static __device__ __forceinline__ float bf_hi(unsigned v){ return __uint_as_float(v & 0xffff0000u); }
static __device__ __forceinline__ ushort bf16u(float f){
  __hip_bfloat16 h = __float2bfloat16(f);
  return *reinterpret_cast<ushort*>(&h);
}
static __device__ __forceinline__ unsigned relu_bf2(unsigned v){
  if (v & 0x00008000u) v &= 0xFFFF0000u;
  if (v & 0x80000000u) v &= 0x0000FFFFu;
  return v;
}

// fused: zero counts+cursor (nz ints) || transpose+convert W1,W2 -> bf16 W^T
__global__ __launch_bounds__(256) void k_init(int* __restrict__ counts2, int nz,
                                              const float* __restrict__ W1,
                                              const float* __restrict__ W2,
                                              ushort* __restrict__ Wt1,
                                              ushort* __restrict__ Wt2){
  const int nzb = (nz + 255) >> 8;
  const int b = blockIdx.x;
  if (b < nzb){
    int i = b*256 + threadIdx.x;
    if (i < nz) counts2[i] = 0;
  } else {
    int i = (b - nzb)*256 + threadIdx.x;   // [0, 32768)
    int sel = i >> 14;
    int rem = i & 16383;
    int k = rem >> 7, n = rem & 127;
    const float* Ws = sel ? W2 : W1;
    ushort* Wd = sel ? Wt2 : Wt1;
    Wd[n*128 + k] = bf16u(Ws[rem]);
  }
}

// histogram, 2 edges/thread via int2
__global__ __launch_bounds__(256) void k_hist(const int* __restrict__ dst,
                                              int* __restrict__ counts, int E){
  int i = blockIdx.x*256 + threadIdx.x;
  int e0 = 2*i;
  if (e0 + 1 < E){
    int2 d = ((const int2*)dst)[i];
    atomicAdd(counts + d.x, 1);
    atomicAdd(counts + d.y, 1);
  } else if (e0 < E){
    atomicAdd(counts + dst[e0], 1);
  }
}

// per-block scan: rowPtr2[i] = {block-local beg, block-local end}; bsum; dinv
__global__ __launch_bounds__(256) void k_scan1(const int* __restrict__ counts,
                                               int2* __restrict__ rowPtr2,
                                               int* __restrict__ bsum,
                                               float* __restrict__ dinv, int n){
  const int i = blockIdx.x*256 + threadIdx.x;
  const int lane = threadIdx.x & 63;
  const int wid  = threadIdx.x >> 6;
  int v = (i < n) ? counts[i] : 0;
  if (i < n) dinv[i] = rsqrtf((float)(v + 1));   // +1 self-loop
  int s = v;
  #pragma unroll
  for (int off = 1; off < 64; off <<= 1){
    int u = __shfl_up(s, off, 64);
    if (lane >= off) s += u;
  }
  __shared__ int ws[4];
  if (lane == 63) ws[wid] = s;
  __syncthreads();
  int add = 0;
  if (wid >= 1) add += ws[0];
  if (wid >= 2) add += ws[1];
  if (wid >= 3) add += ws[2];
  int incl = s + add;
  if (i < n) rowPtr2[i] = make_int2(incl - v, incl);
  if (threadIdx.x == 255) bsum[blockIdx.x] = incl;
}

// single block: exclusive scan of bsum[0..nb), nb <= 256
__global__ __launch_bounds__(256) void k_scan2(int* __restrict__ bsum, int nb){
  const int t = threadIdx.x;
  const int lane = t & 63;
  const int wid  = t >> 6;
  int v = (t < nb) ? bsum[t] : 0;
  int s = v;
  #pragma unroll
  for (int off = 1; off < 64; off <<= 1){
    int u = __shfl_up(s, off, 64);
    if (lane >= off) s += u;
  }
  __shared__ int ws[4];
  if (lane == 63) ws[wid] = s;
  __syncthreads();
  int add = 0;
  if (wid >= 1) add += ws[0];
  if (wid >= 2) add += ws[1];
  if (wid >= 3) add += ws[2];
  int incl = s + add;
  if (t < nb) bsum[t] = incl - v;     // exclusive block offset
}

// scatter edge -> CSR slot (bsum added inline); store {src, dinv[src]}
__global__ __launch_bounds__(256) void k_scatter(const int* __restrict__ src,
                                                 const int* __restrict__ dst,
                                                 const int2* __restrict__ rowPtr2,
                                                 const int* __restrict__ bsum,
                                                 const float* __restrict__ dinv,
                                                 int* __restrict__ cursor,
                                                 int2* __restrict__ edat, int E){
  int i = blockIdx.x*256 + threadIdx.x;
  if (i >= E) return;
  int d = dst[i];
  int s = src[i];
  int pos = rowPtr2[d].x + bsum[d >> 8] + atomicAdd(cursor + d, 1);
  edat[pos] = make_int2(s, __float_as_int(dinv[s]));
}

// C(bf16)[M,128] = maybe_relu(A) @ W, via MFMA 16x16x32 bf16 (R7-proven).
template<bool BF16IN, bool RELU>
__global__ __launch_bounds__(256) void k_gemm_mfma(const void* __restrict__ Av,
                                                   const ushort* __restrict__ Wt,
                                                   __hip_bfloat16* __restrict__ C,
                                                   int M){
  __shared__ ushort sA[64*136];
  __shared__ ushort sW[128*136];
  const int tid = threadIdx.x;
  const int row0 = blockIdx.x * 64;
  const int rowsHere = (M - row0 >= 64) ? 64 : (M - row0);

  {
    const uint4* Wt4 = (const uint4*)Wt;
    for (int i = tid; i < 2048; i += 256){
      int r = i >> 4, c = i & 15;
      uint4 v = Wt4[i];
      *((uint4*)(sW + r*136 + c*8)) = v;
    }
  }
  if (BF16IN){
    const uint4* A4 = (const uint4*)((const ushort*)Av + (size_t)row0 * D);
    for (int i = tid; i < 64*16; i += 256){
      int r = i >> 4, c = i & 15;
      uint4 v = make_uint4(0,0,0,0);
      if (r < rowsHere) v = A4[i];
      if (RELU){ v.x = relu_bf2(v.x); v.y = relu_bf2(v.y);
                 v.z = relu_bf2(v.z); v.w = relu_bf2(v.w); }
      *((uint4*)(sA + r*136 + c*8)) = v;
    }
  } else {
    const float4* A4 = (const float4*)Av + (size_t)row0 * 32;
    for (int i = tid; i < 64*32; i += 256){
      int r = i >> 5, c = i & 31;
      float4 v = make_float4(0.f,0.f,0.f,0.f);
      if (r < rowsHere) v = A4[i];
      if (RELU){ v.x=relu(v.x); v.y=relu(v.y); v.z=relu(v.z); v.w=relu(v.w); }
      ushort4 p;
      p.x = bf16u(v.x); p.y = bf16u(v.y); p.z = bf16u(v.z); p.w = bf16u(v.w);
      *((ushort4*)(sA + r*136 + c*4)) = p;
    }
  }
  __syncthreads();

  const int wid  = tid >> 6;
  const int lane = tid & 63;
  const int fr = lane & 15;
  const int fq = lane >> 4;
  const ushort* aBase = sA + (wid*16 + fr)*136 + fq*8;
  const ushort* wBase = sW + fr*136 + fq*8;

  f32x4 acc0 = {0.f,0.f,0.f,0.f}, acc1 = acc0, acc2 = acc0, acc3 = acc0;
  f32x4 acc4 = acc0, acc5 = acc0, acc6 = acc0, acc7 = acc0;
  #pragma unroll
  for (int ks = 0; ks < 4; ++ks){
    bf16x8 a = *(const bf16x8*)(aBase + ks*32);
    bf16x8 b;
    b = *(const bf16x8*)(wBase + 0*16*136 + ks*32);
    acc0 = __builtin_amdgcn_mfma_f32_16x16x32_bf16(a, b, acc0, 0, 0, 0);
    b = *(const bf16x8*)(wBase + 1*16*136 + ks*32);
    acc1 = __builtin_amdgcn_mfma_f32_16x16x32_bf16(a, b, acc1, 0, 0, 0);
    b = *(const bf16x8*)(wBase + 2*16*136 + ks*32);
    acc2 = __builtin_amdgcn_mfma_f32_16x16x32_bf16(a, b, acc2, 0, 0, 0);
    b = *(const bf16x8*)(wBase + 3*16*136 + ks*32);
    acc3 = __builtin_amdgcn_mfma_f32_16x16x32_bf16(a, b, acc3, 0, 0, 0);
    b = *(const bf16x8*)(wBase + 4*16*136 + ks*32);
    acc4 = __builtin_amdgcn_mfma_f32_16x16x32_bf16(a, b, acc4, 0, 0, 0);
    b = *(const bf16x8*)(wBase + 5*16*136 + ks*32);
    acc5 = __builtin_amdgcn_mfma_f32_16x16x32_bf16(a, b, acc5, 0, 0, 0);
    b = *(const bf16x8*)(wBase + 6*16*136 + ks*32);
    acc6 = __builtin_amdgcn_mfma_f32_16x16x32_bf16(a, b, acc6, 0, 0, 0);
    b = *(const bf16x8*)(wBase + 7*16*136 + ks*32);
    acc7 = __builtin_amdgcn_mfma_f32_16x16x32_bf16(a, b, acc7, 0, 0, 0);
  }

  const int rbase = row0 + wid*16 + fq*4;
  #pragma unroll
  for (int r = 0; r < 4; ++r){
    int row = rbase + r;
    if (row < M){
      __hip_bfloat16* crow = C + (size_t)row*D + fr;
      crow[0*16]  = __float2bfloat16(acc0[r]);
      crow[1*16]  = __float2bfloat16(acc1[r]);
      crow[2*16]  = __float2bfloat16(acc2[r]);
      crow[3*16]  = __float2bfloat16(acc3[r]);
      crow[4*16]  = __float2bfloat16(acc4[r]);
      crow[5*16]  = __float2bfloat16(acc5[r]);
      crow[6*16]  = __float2bfloat16(acc6[r]);
      crow[7*16]  = __float2bfloat16(acc7[r]);
    }
  }
}

// R7/R10-proven bf16 gather core (4 edges/step via 16-lane groups, unroll 2),
// beg/end from rowPtr2 + inline bsum.
#define AGG_CORE_BF16                                                          \
  const int grp = lane >> 4;                                                   \
  const int q   = lane & 15;                                                   \
  float dn = dinv[node];                                                       \
  float4 aA0 = make_float4(0,0,0,0), aB0 = aA0, aA1 = aA0, aB1 = aA0;          \
  int2 be = rowPtr2[node];                                                     \
  int bs = bsum[node >> 8];                                                    \
  int beg = be.x + bs, end = be.y + bs;                                        \
  for (int j = beg; j < end; j += 64){                                         \
    int rem = end - j;                                                         \
    int cnt = (rem < 64) ? rem : 64;                                           \
    int2 ed = make_int2(0, 0);                                                 \
    if (lane < cnt) ed = edat[j + lane];                                       \
    int T = (((cnt + 3) >> 2) + 1) & ~1;                                       \
    for (int t = 0; t < T; t += 2){                                            \
      _Pragma("unroll")                                                        \
      for (int u = 0; u < 2; ++u){                                             \
        int e = 4*(t+u) + grp;                                                 \
        int sb = __shfl(ed.x, e);                                              \
        float nb = __uint_as_float((unsigned)__shfl(ed.y, e)) * dn;            \
        uint4 hv = ((const uint4*)(h + (size_t)sb*D))[q];                      \
        float4& cA = u ? aA1 : aA0;                                            \
        float4& cB = u ? aB1 : aB0;                                            \
        cA.x += bf_lo(hv.x)*nb; cA.y += bf_hi(hv.x)*nb;                        \
        cA.z += bf_lo(hv.y)*nb; cA.w += bf_hi(hv.y)*nb;                        \
        cB.x += bf_lo(hv.z)*nb; cB.y += bf_hi(hv.z)*nb;                        \
        cB.z += bf_lo(hv.w)*nb; cB.w += bf_hi(hv.w)*nb;                        \
      }                                                                        \
    }                                                                          \
  }                                                                            \
  float4 rA, rB;                                                               \
  rA.x=aA0.x+aA1.x; rA.y=aA0.y+aA1.y; rA.z=aA0.z+aA1.z; rA.w=aA0.w+aA1.w;      \
  rB.x=aB0.x+aB1.x; rB.y=aB0.y+aB1.y; rB.z=aB0.z+aB1.z; rB.w=aB0.w+aB1.w;      \
  rA.x += __shfl_xor(rA.x,16,64); rA.y += __shfl_xor(rA.y,16,64);              \
  rA.z += __shfl_xor(rA.z,16,64); rA.w += __shfl_xor(rA.w,16,64);              \
  rB.x += __shfl_xor(rB.x,16,64); rB.y += __shfl_xor(rB.y,16,64);              \
  rB.z += __shfl_xor(rB.z,16,64); rB.w += __shfl_xor(rB.w,16,64);              \
  rA.x += __shfl_xor(rA.x,32,64); rA.y += __shfl_xor(rA.y,32,64);              \
  rA.z += __shfl_xor(rA.z,32,64); rA.w += __shfl_xor(rA.w,32,64);              \
  rB.x += __shfl_xor(rB.x,32,64); rB.y += __shfl_xor(rB.y,32,64);              \
  rB.z += __shfl_xor(rB.z,32,64); rB.w += __shfl_xor(rB.w,32,64);

// layer-1 agg: out(bf16)[node] = h*dinv^2 + b + gathered
__global__ __launch_bounds__(256) void k_agg_csr(const ushort* __restrict__ h,
                                                 const int2* __restrict__ rowPtr2,
                                                 const int* __restrict__ bsum,
                                                 const int2* __restrict__ edat,
                                                 const float* __restrict__ dinv,
                                                 const float* __restrict__ b,
                                                 ushort* __restrict__ out, int n){
  int gid = blockIdx.x*256 + threadIdx.x;
  int node = gid >> 6;
  int lane = gid & 63;
  if (node >= n) return;
  AGG_CORE_BF16
  if (grp != 0) return;
  uint4 hs = ((const uint4*)(h + (size_t)node*D))[q];
  float sl = dn * dn;
  float4 bA = ((const float4*)b)[2*q];
  float4 bB = ((const float4*)b)[2*q + 1];
  float r[8];
  r[0] = rA.x + bf_lo(hs.x)*sl + bA.x;
  r[1] = rA.y + bf_hi(hs.x)*sl + bA.y;
  r[2] = rA.z + bf_lo(hs.y)*sl + bA.z;
  r[3] = rA.w + bf_hi(hs.y)*sl + bA.w;
  r[4] = rB.x + bf_lo(hs.z)*sl + bB.x;
  r[5] = rB.y + bf_hi(hs.z)*sl + bB.y;
  r[6] = rB.z + bf_lo(hs.w)*sl + bB.z;
  r[7] = rB.w + bf_hi(hs.w)*sl + bB.w;
  union Pack { uint4 u; __hip_bfloat16 b[8]; } p;
  #pragma unroll
  for (int i = 0; i < 8; ++i) p.b[i] = __float2bfloat16(r[i]);
  ((uint4*)(out + (size_t)node*D))[q] = p.u;
}

// layer-2 agg fused with head: relu(agg) @ Wl + bl -> log_softmax
__global__ __launch_bounds__(256) void k_agg_head(const ushort* __restrict__ h,
                                                  const int2* __restrict__ rowPtr2,
                                                  const int* __restrict__ bsum,
                                                  const int2* __restrict__ edat,
                                                  const float* __restrict__ dinv,
                                                  const float* __restrict__ b,
                                                  const float* __restrict__ Wl,
                                                  const float* __restrict__ bl,
                                                  float* __restrict__ out, int n){
  int gid = blockIdx.x*256 + threadIdx.x;
  int node = gid >> 6;
  int lane = gid & 63;
  if (node >= n) return;
  AGG_CORE_BF16
  if (grp != 0) return;
  uint4 hs = ((const uint4*)(h + (size_t)node*D))[q];
  float sl = dn * dn;
  float4 bA = ((const float4*)b)[2*q];
  float4 bB = ((const float4*)b)[2*q + 1];
  float r[8];
  r[0] = relu(rA.x + bf_lo(hs.x)*sl + bA.x);
  r[1] = relu(rA.y + bf_hi(hs.x)*sl + bA.y);
  r[2] = relu(rA.z + bf_lo(hs.y)*sl + bA.z);
  r[3] = relu(rA.w + bf_hi(hs.y)*sl + bA.w);
  r[4] = relu(rB.x + bf_lo(hs.z)*sl + bB.x);
  r[5] = relu(rB.y + bf_hi(hs.z)*sl + bB.y);
  r[6] = relu(rB.z + bf_lo(hs.w)*sl + bB.z);
  r[7] = relu(rB.w + bf_hi(hs.w)*sl + bB.w);
  float lacc[NCLS];
  #pragma unroll
  for (int c = 0; c < NCLS; ++c){
    float a = 0.f;
    #pragma unroll
    for (int i = 0; i < 8; ++i) a += r[i] * Wl[(8*q + i)*NCLS + c];
    lacc[c] = a;
  }
  #pragma unroll
  for (int c = 0; c < NCLS; ++c){
    #pragma unroll
    for (int off = 8; off >= 1; off >>= 1)
      lacc[c] += __shfl_xor(lacc[c], off, 16);
    lacc[c] += bl[c];
  }
  float m = lacc[0];
  #pragma unroll
  for (int c = 1; c < NCLS; ++c) m = fmaxf(m, lacc[c]);
  float se = 0.f;
  #pragma unroll
  for (int c = 0; c < NCLS; ++c) se += expf(lacc[c] - m);
  float lse = m + logf(se);
  if (q < NCLS){
    float v = lacc[0];
    #pragma unroll
    for (int c = 1; c < NCLS; ++c) if (q == c) v = lacc[c];
    out[(size_t)node*NCLS + q] = v - lse;
  }
}

extern "C" void kernel_launch(void* const* d_in, const int* in_sizes, int n_in,
                              void* d_out, int out_size, void* d_ws, size_t ws_size,
                              hipStream_t stream){
  const float* x  = (const float*)d_in[0];
  const int*   ei = (const int*)d_in[1];
  const float* W1 = (const float*)d_in[2];
  const float* b1 = (const float*)d_in[3];
  const float* W2 = (const float*)d_in[4];
  const float* b2 = (const float*)d_in[5];
  const float* Wl = (const float*)d_in[6];
  const float* bl = (const float*)d_in[7];
  float* out = (float*)d_out;

  const int N = in_sizes[0] / D;     // 50000
  const int E = in_sizes[1] / 2;     // 800000
  const int* src = ei;
  const int* dst = ei + E;

  char* ws = (char*)d_ws;
  size_t off = 0;
  ushort* h1    = (ushort*)(ws + off); off += (size_t)N*D*2;
  ushort* g1    = (ushort*)(ws + off); off += (size_t)N*D*2;
  ushort* h2    = (ushort*)(ws + off); off += (size_t)N*D*2;
  ushort* Wt1   = (ushort*)(ws + off); off += (size_t)128*128*2;
  ushort* Wt2   = (ushort*)(ws + off); off += (size_t)128*128*2;
  int*   counts = (int*)(ws + off);    off += (size_t)N*4;
  int*   cursor = (int*)(ws + off);    off += (size_t)N*4;    // adjacent to counts
  int2*  rowPtr2= (int2*)(ws + off);   off += (size_t)N*8;
  float* dinv   = (float*)(ws + off);  off += (size_t)N*4;
  int*   bsum   = (int*)(ws + off);    off += (size_t)256*4;
  int2*  edat   = (int2*)(ws + off);   off += (size_t)E*8;

  const int nbN   = (N + 255)/256;     // 196 (<=256 for scan2)
  const int nb2N  = (2*N + 255)/256;   // 391
  const int nbE   = (E + 255)/256;
  const int nbE2  = (E/2 + 255)/256;
  const int initB = nb2N + 128;        // zero || cvtW
  const int gemmB = (N + 63)/64;
  const int aggB  = (N + 3)/4;         // 1 wave per node

  // CSR build + weight transpose (9 dispatches total this launch)
  k_init<<<initB, 256, 0, stream>>>(counts, 2*N, W1, W2, Wt1, Wt2);
  k_hist<<<nbE2, 256, 0, stream>>>(dst, counts, E);
  k_scan1<<<nbN, 256, 0, stream>>>(counts, rowPtr2, bsum, dinv, N);
  k_scan2<<<1, 256, 0, stream>>>(bsum, nbN);
  k_scatter<<<nbE, 256, 0, stream>>>(src, dst, rowPtr2, bsum, dinv, cursor, edat, E);

  // layer 1
  k_gemm_mfma<false,false><<<gemmB, 256, 0, stream>>>(x, Wt1, (__hip_bfloat16*)h1, N);
  k_agg_csr<<<aggB, 256, 0, stream>>>(h1, rowPtr2, bsum, edat, dinv, b1, g1, N);

  // layer 2 (relu fused into GEMM staging; head fused into aggregation)
  k_gemm_mfma<true,true><<<gemmB, 256, 0, stream>>>(g1, Wt2, (__hip_bfloat16*)h2, N);
  k_agg_head<<<aggB, 256, 0, stream>>>(h2, rowPtr2, bsum, edat, dinv, b2, Wl, bl, out, N);
}